// Round 5
// baseline (124.985 us; speedup 1.0000x reference)
//
#include <hip/hip_runtime.h>
#include <math.h>

#define LEAK 0.2f

__device__ __forceinline__ float leaky_f(float x) { return x >= 0.0f ? x : LEAK * x; }
__device__ __forceinline__ float sigmoid_f(float x) { return 1.0f / (1.0f + expf(-x)); }

// Intra-wave LDS fence (R3-proven): orders this wave's LDS writes before its
// subsequent reads without a workgroup barrier.
__device__ __forceinline__ void wave_lds_fence() {
    __builtin_amdgcn_wave_barrier();
    __threadfence_block();
    __builtin_amdgcn_wave_barrier();
}

// LDS weight-staging offsets (floats); every segment start %4==0.
#define OP1  0        // W_P1 128x64 = 8192
#define OP2  8192     // W_P2 64x32  = 2048
#define OP3  10240    // W_P3 32x16  = 512
#define OP4  10752    // W_P4 16x8   = 128
#define OP5  10880    // W_P5 8x3    = 24
#define OB1  10904    // b_P1 64
#define OB2  10968    // b_P2 32
#define OB3  11000    // b_P3 16
#define OB4  11016    // b_P4 8
#define OBL  11024    // b_l  512
#define OB5  11536    // b_P5 3 (pad 4)
#define OS1  11540    // W_S1 58x32 = 1856
#define OS2  13396    // W_S2 32x64 = 2048
#define OM1  15444    // W_M1 6x8   = 48
#define OT1  15492    // W_T1 11x8  = 88
#define OM2  15580    // W_M2 8x16  = 128
#define OT2  15708    // W_T2 8x16  = 128
#define OBM1 15836    // b_M1 8
#define OBT1 15844    // b_T1 8
#define OBM2 15852    // b_M2 16
#define OBT2 15868    // b_T2 16
#define OBS1 15884    // b_S1 32
#define OBS2 15916    // b_S2 64
#define WLS_N 15980

// One block per batch (B=32), 512 threads. Only t=0,1,2 matter (output is
// out[:, 2:3, :]). ALL global reads are issued at T=0:
//   - Wk quarter -> 31 float4 regs/thread (consumed at stage F, then dead)
//   - every small weight + bias -> LDS via float4 staging (threads 192-511)
//   - data[b,0:3,:] -> LDS
// Stages B-E run wave-0-only with intra-wave fences (no block barriers).
// Wr -> 32 float4 regs/thread, issued inside the zx/t0 phase so the drain
// hides behind that phase; LSTM + head then do zero global loads.
__global__ __launch_bounds__(512)
void lstm_cls_kernel(const float* __restrict__ data,
                     const float* __restrict__ W_M1, const float* __restrict__ b_M1,
                     const float* __restrict__ W_M2, const float* __restrict__ b_M2,
                     const float* __restrict__ W_T1, const float* __restrict__ b_T1,
                     const float* __restrict__ W_T2, const float* __restrict__ b_T2,
                     const float* __restrict__ W_S1, const float* __restrict__ b_S1,
                     const float* __restrict__ W_S2, const float* __restrict__ b_S2,
                     const float* __restrict__ Wk,   const float* __restrict__ b_l,
                     const float* __restrict__ Wr,
                     const float* __restrict__ W_P1, const float* __restrict__ b_P1,
                     const float* __restrict__ W_P2, const float* __restrict__ b_P2,
                     const float* __restrict__ W_P3, const float* __restrict__ b_P3,
                     const float* __restrict__ W_P4, const float* __restrict__ b_P4,
                     const float* __restrict__ W_P5, const float* __restrict__ b_P5,
                     float* __restrict__ out)
{
    __shared__ float sdata[3][11];
    __shared__ float feat[3][124];     // [M(16) Tsk(16) Psk(16) Pa(1) S(64) data(11)]
    __shared__ float m1s[3][8];
    __shared__ float t1s[3][8];
    __shared__ float s1s[3][32];
    __shared__ float zpart[4][3][512]; // stage F / LSTM split-K partials
    __shared__ float zx[2][512];       // z-input for t=1,2 (t=0 consumed inline)
    __shared__ float h[128];
    __shared__ float pp[8][64];
    __shared__ float d1[64], d2[32], d3[16], d4[8], smx[3];
    __shared__ float wls[WLS_N];

    const int b   = blockIdx.x;
    const int tid = threadIdx.x;
    const int q   = tid >> 7;       // 0..3: k-quarter
    const int c4  = tid & 127;      // float4 column group
    const float* db = data + (size_t)b * 4096 * 11;

    // ===================== T=0: issue ALL global loads =====================
    // Wk quarter -> registers (31 float4, all in flight at once).
    const float4* Wk4 = (const float4*)Wk;
    float4 kw[31];
    #pragma unroll
    for (int i = 0; i < 31; ++i)
        kw[i] = Wk4[(31 * q + i) * 128 + c4];

    // data[b, 0:3, :]
    if (tid < 33) {
        int t = tid / 11, k = tid % 11;
        float v = db[t * 11 + k];
        sdata[t][k] = v;
        feat[t][113 + k] = v;
    }

    // All small weights + biases -> LDS (float4), threads 192-511.
    if (tid >= 192) {
        int wi = tid - 192;                       // 0..319
        float4* wls4 = (float4*)wls;
        for (int i = wi; i < 2048; i += 320) wls4[OP1/4  + i] = ((const float4*)W_P1)[i];
        for (int i = wi; i < 512;  i += 320) wls4[OP2/4  + i] = ((const float4*)W_P2)[i];
        for (int i = wi; i < 128;  i += 320) wls4[OP3/4  + i] = ((const float4*)W_P3)[i];
        for (int i = wi; i < 32;   i += 320) wls4[OP4/4  + i] = ((const float4*)W_P4)[i];
        for (int i = wi; i < 6;    i += 320) wls4[OP5/4  + i] = ((const float4*)W_P5)[i];
        for (int i = wi; i < 16;   i += 320) wls4[OB1/4  + i] = ((const float4*)b_P1)[i];
        for (int i = wi; i < 8;    i += 320) wls4[OB2/4  + i] = ((const float4*)b_P2)[i];
        for (int i = wi; i < 4;    i += 320) wls4[OB3/4  + i] = ((const float4*)b_P3)[i];
        for (int i = wi; i < 2;    i += 320) wls4[OB4/4  + i] = ((const float4*)b_P4)[i];
        for (int i = wi; i < 128;  i += 320) wls4[OBL/4  + i] = ((const float4*)b_l)[i];
        for (int i = wi; i < 464;  i += 320) wls4[OS1/4  + i] = ((const float4*)W_S1)[i];
        for (int i = wi; i < 512;  i += 320) wls4[OS2/4  + i] = ((const float4*)W_S2)[i];
        for (int i = wi; i < 12;   i += 320) wls4[OM1/4  + i] = ((const float4*)W_M1)[i];
        for (int i = wi; i < 22;   i += 320) wls4[OT1/4  + i] = ((const float4*)W_T1)[i];
        for (int i = wi; i < 32;   i += 320) wls4[OM2/4  + i] = ((const float4*)W_M2)[i];
        for (int i = wi; i < 32;   i += 320) wls4[OT2/4  + i] = ((const float4*)W_T2)[i];
        for (int i = wi; i < 2;    i += 320) wls4[OBM1/4 + i] = ((const float4*)b_M1)[i];
        for (int i = wi; i < 2;    i += 320) wls4[OBT1/4 + i] = ((const float4*)b_T1)[i];
        for (int i = wi; i < 4;    i += 320) wls4[OBM2/4 + i] = ((const float4*)b_M2)[i];
        for (int i = wi; i < 4;    i += 320) wls4[OBT2/4 + i] = ((const float4*)b_T2)[i];
        for (int i = wi; i < 8;    i += 320) wls4[OBS1/4 + i] = ((const float4*)b_S1)[i];
        for (int i = wi; i < 16;   i += 320) wls4[OBS2/4 + i] = ((const float4*)b_S2)[i];
        if (wi < 3) wls[OB5 + wi] = b_P5[wi];
    }
    __syncthreads();   // barrier-1: data + staged weights visible

    // ============ stages B-E: wave 0 only, intra-wave fences ============
    if (tid < 64) {
        // ---- stage B ----
        if (tid < 24) {
            int t = tid / 8, j = tid & 7;
            float acc = wls[OBM1 + j];
            #pragma unroll
            for (int k = 0; k < 6; ++k) acc = fmaf(sdata[t][4 + k], wls[OM1 + k * 8 + j], acc);
            m1s[t][j] = leaky_f(acc);
        } else if (tid < 48) {
            int u = tid - 24, t = u / 8, j = u & 7;
            float acc = wls[OBT1 + j];
            #pragma unroll
            for (int k = 0; k < 11; ++k) acc = fmaf(sdata[t][k], wls[OT1 + k * 8 + j], acc);
            t1s[t][j] = fabsf(leaky_f(acc));
        } else if (tid < 51) {
            int t = tid - 48;
            feat[t][48] = log1pf(sdata[t][1]);   // Pa
        }
        wave_lds_fence();

        // ---- stage C: 96 tasks, 2 rounds ----
        #pragma unroll
        for (int r = 0; r < 2; ++r) {
            int idx = tid + 64 * r;
            if (idx < 48) {
                int t = idx / 16, j = idx & 15;
                float acc = wls[OBM2 + j];
                #pragma unroll
                for (int k = 0; k < 8; ++k) acc = fmaf(m1s[t][k], wls[OM2 + k * 16 + j], acc);
                feat[t][j] = leaky_f(acc);                  // M
            } else if (idx < 96) {
                int u = idx - 48, t = u / 16, j = u & 15;
                float acc = wls[OBT2 + j];
                #pragma unroll
                for (int k = 0; k < 8; ++k) acc = fmaf(t1s[t][k], wls[OT2 + k * 16 + j], acc);
                float v = fabsf(leaky_f(acc));
                feat[t][16 + j] = v;                        // Tsk
                feat[t][32 + j] = log1pf(v);                // Psk
            }
        }
        wave_lds_fence();

        // ---- stage D: s1 = leaky(s_in @ W_S1 + b), 96 tasks, 2 rounds ----
        #pragma unroll
        for (int r = 0; r < 2; ++r) {
            int idx = tid + 64 * r;
            if (idx < 96) {
                int t = idx >> 5, j = idx & 31;
                float acc = wls[OBS1 + j];
                for (int k = 0; k < 49; ++k) acc = fmaf(feat[t][k], wls[OS1 + k * 32 + j], acc);
                #pragma unroll
                for (int k = 49; k < 58; ++k) acc = fmaf(sdata[t][k - 48], wls[OS1 + k * 32 + j], acc);
                s1s[t][j] = leaky_f(acc);
            }
        }
        wave_lds_fence();

        // ---- stage E: S = leaky(s1 @ W_S2 + b), 192 tasks, 3 rounds ----
        #pragma unroll
        for (int r = 0; r < 3; ++r) {
            int idx = tid + 64 * r;
            int t = idx >> 6, j = idx & 63;
            float acc = wls[OBS2 + j];
            #pragma unroll
            for (int k = 0; k < 32; ++k) acc = fmaf(s1s[t][k], wls[OS2 + k * 64 + j], acc);
            feat[t][49 + j] = leaky_f(acc);
        }
    }
    __syncthreads();   // barrier-2: feat complete

    // ---- stage F: zx partials from kw registers (zero loads) ----
    {
        float4 f0 = make_float4(0.f,0.f,0.f,0.f), f1 = f0, f2 = f0;
        #pragma unroll
        for (int i = 0; i < 31; ++i) {
            int k = 31 * q + i;
            float4 w = kw[i];
            float a = feat[0][k], bb = feat[1][k], cc = feat[2][k];
            f0.x = fmaf(a,  w.x, f0.x); f0.y = fmaf(a,  w.y, f0.y);
            f0.z = fmaf(a,  w.z, f0.z); f0.w = fmaf(a,  w.w, f0.w);
            f1.x = fmaf(bb, w.x, f1.x); f1.y = fmaf(bb, w.y, f1.y);
            f1.z = fmaf(bb, w.z, f1.z); f1.w = fmaf(bb, w.w, f1.w);
            f2.x = fmaf(cc, w.x, f2.x); f2.y = fmaf(cc, w.y, f2.y);
            f2.z = fmaf(cc, w.z, f2.z); f2.w = fmaf(cc, w.w, f2.w);
        }
        ((float4*)&zpart[q][0][0])[c4] = f0;
        ((float4*)&zpart[q][1][0])[c4] = f1;
        ((float4*)&zpart[q][2][0])[c4] = f2;
    }
    __syncthreads();   // barrier-3: zpart visible (kw dead)

    // ---- zx(t=1,2) reduce + LSTM t=0 inline; Wr regs issued here so their
    //      drain hides behind this phase ----
    const float4* Wr4 = (const float4*)Wr;
    float4 rw[32];
    #pragma unroll
    for (int kk = 0; kk < 32; ++kk)
        rw[kk] = Wr4[(32 * q + kk) * 128 + c4];

    float c = 0.0f;
    #pragma unroll
    for (int r = 0; r < 2; ++r) {   // 1024 tasks over 512 threads
        int task = tid + 512 * r;
        int t = task >> 9, col = task & 511;
        zx[t][col] = wls[OBL + col] + zpart[0][1 + t][col] + zpart[1][1 + t][col]
                   + zpart[2][1 + t][col] + zpart[3][1 + t][col];
    }
    if (tid < 128) {   // LSTM t=0 (h=c=0): z = b_l + F-partials, gate directly
        int j = tid;
        float zi = wls[OBL + j]       + zpart[0][0][j]       + zpart[1][0][j]       + zpart[2][0][j]       + zpart[3][0][j];
        float zg = wls[OBL + 256 + j] + zpart[0][0][256 + j] + zpart[1][0][256 + j] + zpart[2][0][256 + j] + zpart[3][0][256 + j];
        float zo = wls[OBL + 384 + j] + zpart[0][0][384 + j] + zpart[1][0][384 + j] + zpart[2][0][384 + j] + zpart[3][0][384 + j];
        c = sigmoid_f(zi) * leaky_f(zg);
        h[j] = sigmoid_f(zo) * leaky_f(c);
    }
    __syncthreads();   // barrier-4: h(t=0), zx ready; rw drained

    // ---- LSTM t=1,2: matvec from rw registers (zero loads) ----
    for (int t = 0; t < 2; ++t) {
        float4 acc = make_float4(0.f, 0.f, 0.f, 0.f);
        #pragma unroll
        for (int kk = 0; kk < 32; ++kk) {
            float hk = h[32 * q + kk];          // wave-uniform LDS broadcast
            acc.x = fmaf(hk, rw[kk].x, acc.x);
            acc.y = fmaf(hk, rw[kk].y, acc.y);
            acc.z = fmaf(hk, rw[kk].z, acc.z);
            acc.w = fmaf(hk, rw[kk].w, acc.w);
        }
        ((float4*)&zpart[q][0][0])[c4] = acc;
        __syncthreads();
        if (tid < 128) {
            int j = tid;
            float zi = zx[t][j]       + zpart[0][0][j]       + zpart[1][0][j]       + zpart[2][0][j]       + zpart[3][0][j];
            float zf = zx[t][128 + j] + zpart[0][0][128 + j] + zpart[1][0][128 + j] + zpart[2][0][128 + j] + zpart[3][0][128 + j];
            float zg = zx[t][256 + j] + zpart[0][0][256 + j] + zpart[1][0][256 + j] + zpart[2][0][256 + j] + zpart[3][0][256 + j];
            float zo = zx[t][384 + j] + zpart[0][0][384 + j] + zpart[1][0][384 + j] + zpart[2][0][384 + j] + zpart[3][0][384 + j];
            c = sigmoid_f(zf) * c + sigmoid_f(zi) * leaky_f(zg);
            h[j] = sigmoid_f(zo) * leaky_f(c);
        }
        __syncthreads();
    }

    // ---- head (weights in LDS) ----
    {   // 128 -> 64, split-K 8x16
        int part = tid >> 6, jj = tid & 63;
        float acc = 0.0f;
        #pragma unroll
        for (int i = 0; i < 16; ++i) {
            int k = part * 16 + i;
            acc = fmaf(h[k], wls[OP1 + k * 64 + jj], acc);
        }
        pp[part][jj] = acc;
    }
    __syncthreads();
    if (tid < 64) {
        float acc = wls[OB1 + tid];
        #pragma unroll
        for (int p = 0; p < 8; ++p) acc += pp[p][tid];
        d1[tid] = leaky_f(acc);
    }
    __syncthreads();
    if (tid < 256) {   // 64 -> 32, split-K 8x8
        int part = tid >> 5, jj = tid & 31;
        float acc = 0.0f;
        #pragma unroll
        for (int i = 0; i < 8; ++i) {
            int k = part * 8 + i;
            acc = fmaf(d1[k], wls[OP2 + k * 32 + jj], acc);
        }
        pp[part][jj] = acc;
    }
    __syncthreads();
    if (tid < 32) {
        float acc = wls[OB2 + tid];
        #pragma unroll
        for (int p = 0; p < 8; ++p) acc += pp[p][tid];
        d2[tid] = leaky_f(acc);
    }
    __syncthreads();
    if (tid < 128) {   // 32 -> 16, split-K 8x4
        int part = tid >> 4, jj = tid & 15;
        float acc = 0.0f;
        #pragma unroll
        for (int i = 0; i < 4; ++i) {
            int k = part * 4 + i;
            acc = fmaf(d2[k], wls[OP3 + k * 16 + jj], acc);
        }
        pp[part][jj] = acc;
    }
    __syncthreads();
    if (tid < 16) {
        float acc = wls[OB3 + tid];
        #pragma unroll
        for (int p = 0; p < 8; ++p) acc += pp[p][tid];
        d3[tid] = leaky_f(acc);
    }
    __syncthreads();
    if (tid < 8) {     // 16 -> 8
        float acc = wls[OB4 + tid];
        #pragma unroll
        for (int k = 0; k < 16; ++k) acc = fmaf(d3[k], wls[OP4 + k * 8 + tid], acc);
        d4[tid] = leaky_f(acc);
    }
    __syncthreads();
    if (tid == 0) {    // 8 -> 3 + softmax
        float l[3], mx = -1e30f;
        #pragma unroll
        for (int r = 0; r < 3; ++r) {
            float acc = wls[OB5 + r];
            #pragma unroll
            for (int k = 0; k < 8; ++k) acc = fmaf(d4[k], wls[OP5 + k * 3 + r], acc);
            l[r] = leaky_f(acc);
            mx = fmaxf(mx, l[r]);
        }
        float s = 0.0f;
        #pragma unroll
        for (int r = 0; r < 3; ++r) { l[r] = expf(l[r] - mx); s += l[r]; }
        float inv = 1.0f / s;
        #pragma unroll
        for (int r = 0; r < 3; ++r) smx[r] = l[r] * inv;
    }
    __syncthreads();

    // ---- outputs: d_out[0:96] = softmax(t=2); d_out[96:512] = x ----
    if (tid < 3)  out[b * 3 + tid] = smx[tid];
    if (tid < 13) {
        float v = (tid < 10) ? sdata[2][1 + tid] : smx[tid - 10];
        out[96 + b * 13 + tid] = v;
    }
}

extern "C" void kernel_launch(void* const* d_in, const int* in_sizes, int n_in,
                              void* d_out, int out_size, void* d_ws, size_t ws_size,
                              hipStream_t stream) {
    const float* data = (const float*)d_in[0];
    const float* W_M1 = (const float*)d_in[1];
    const float* b_M1 = (const float*)d_in[2];
    const float* W_M2 = (const float*)d_in[3];
    const float* b_M2 = (const float*)d_in[4];
    const float* W_T1 = (const float*)d_in[5];
    const float* b_T1 = (const float*)d_in[6];
    const float* W_T2 = (const float*)d_in[7];
    const float* b_T2 = (const float*)d_in[8];
    const float* W_S1 = (const float*)d_in[9];
    const float* b_S1 = (const float*)d_in[10];
    const float* W_S2 = (const float*)d_in[11];
    const float* b_S2 = (const float*)d_in[12];
    const float* Wk   = (const float*)d_in[13];
    const float* Wr   = (const float*)d_in[14];
    const float* b_l  = (const float*)d_in[15];
    const float* W_P1 = (const float*)d_in[16];
    const float* b_P1 = (const float*)d_in[17];
    const float* W_P2 = (const float*)d_in[18];
    const float* b_P2 = (const float*)d_in[19];
    const float* W_P3 = (const float*)d_in[20];
    const float* b_P3 = (const float*)d_in[21];
    const float* W_P4 = (const float*)d_in[22];
    const float* b_P4 = (const float*)d_in[23];
    const float* W_P5 = (const float*)d_in[24];
    const float* b_P5 = (const float*)d_in[25];
    float* out = (float*)d_out;

    lstm_cls_kernel<<<dim3(32), dim3(512), 0, stream>>>(
        data, W_M1, b_M1, W_M2, b_M2, W_T1, b_T1, W_T2, b_T2,
        W_S1, b_S1, W_S2, b_S2, Wk, b_l, Wr,
        W_P1, b_P1, W_P2, b_P2, W_P3, b_P3, W_P4, b_P4, W_P5, b_P5,
        out);
}